// Round 14
// baseline (178.284 us; speedup 1.0000x reference)
//
#include <hip/hip_runtime.h>

typedef float f32x16 __attribute__((ext_vector_type(16)));
typedef short bf16x8 __attribute__((ext_vector_type(8)));
typedef unsigned int u32;

static __device__ __forceinline__ unsigned short f2bf(float f) {
  union { float f; unsigned int u; } v;
  v.f = f;
  return (unsigned short)((v.u + 0x7FFFu + ((v.u >> 16) & 1u)) >> 16);
}

// async 16B global->LDS (DMA). LDS dest = wave-uniform base + lane*16.
static __device__ __forceinline__ void gl_lds16(const unsigned short* g,
                                                unsigned short* l) {
  __builtin_amdgcn_global_load_lds(
      (const __attribute__((address_space(1))) u32*)g,
      (__attribute__((address_space(3))) u32*)l, 16, 0, 0);
}

#define VMCNT3 asm volatile("s_waitcnt vmcnt(3)" ::: "memory")
#define VMCNT2 asm volatile("s_waitcnt vmcnt(2)" ::: "memory")
#define VMCNT0 asm volatile("s_waitcnt vmcnt(0)" ::: "memory")
#define LGKM0 asm volatile("s_waitcnt lgkmcnt(0)" ::: "memory")
#define BAR __builtin_amdgcn_s_barrier()
#define SCHEDB __builtin_amdgcn_sched_barrier(0)

// ---- weights: OIHW fp32 -> [cic][p][tap][co][8ci] bf16; + zero page.
__global__ __launch_bounds__(256) void convert_weights(
    const float* __restrict__ W1, const float* __restrict__ W2,
    unsigned short* __restrict__ W1b, unsigned short* __restrict__ W2b,
    unsigned short* __restrict__ zp) {
  if (blockIdx.x == 1728) {
    uint4* z = (uint4*)zp;
    z[threadIdx.x] = make_uint4(0, 0, 0, 0);
    z[256 + threadIdx.x] = make_uint4(0, 0, 0, 0);
    return;
  }
  int i = blockIdx.x * 256 + threadIdx.x;
  if (i < 294912) {
    int e = i & 7, co = (i >> 3) & 127, r = i >> 10;  // r=(cic*2+p)*9+tap
    int tap = r % 9, pc = r / 9;
    int ci = (pc >> 1) * 16 + (pc & 1) * 8 + e;
    W1b[i] = f2bf(W1[(co * 256 + ci) * 9 + tap]);
  } else {
    int j = i - 294912;
    if (j < 147456) {
      int e = j & 7, co = (j >> 3) & 127, r = j >> 10;
      int tap = r % 9, pc = r / 9;
      int ci = (pc >> 1) * 16 + (pc & 1) * 8 + e;
      W2b[j] = f2bf(W2[(co * 128 + ci) * 9 + tap]);
    }
  }
}

// -- NCHW fp32 -> padded plane-major bf16 [8][128][32 cig][130 px][8 ci] ----
__global__ __launch_bounds__(256) void transpose_to_bf16(
    const float* __restrict__ x, const float* __restrict__ skip,
    unsigned short* __restrict__ dst) {
  int bid = blockIdx.x;
  const float* src = (bid < 1024) ? x : skip;
  int cigb = (bid < 1024) ? 0 : 16;
  int row = bid & 1023;  // b*128+y
  int b = row >> 7, y = row & 127;
  const float* s = src + (long)b * 128 * 16384 + (long)y * 128;
  for (int it = 0; it < 8; ++it) {
    int u = it * 256 + (int)threadIdx.x;
    int cig = u >> 7, px = u & 127;
    unsigned short pk[8];
#pragma unroll
    for (int e = 0; e < 8; ++e)
      pk[e] = f2bf(s[(long)(cig * 8 + e) * 16384 + px]);
    uint4 vv;
    vv.x = (unsigned)pk[0] | ((unsigned)pk[1] << 16);
    vv.y = (unsigned)pk[2] | ((unsigned)pk[3] << 16);
    vv.z = (unsigned)pk[4] | ((unsigned)pk[5] << 16);
    vv.w = (unsigned)pk[6] | ((unsigned)pk[7] << 16);
    *(uint4*)(&dst[(((long)row * 32 + cigb + cig) * 130 + px + 1) * 8]) = vv;
  }
  if (cigb == 0 && threadIdx.x < 64) {  // zero px 0,129 for all 32 cig
    int g = threadIdx.x >> 1;
    long col = (threadIdx.x & 1) * 129L;
    *(uint4*)(&dst[(((long)row * 32 + g) * 130 + col) * 8]) = make_uint4(0, 0, 0, 0);
  }
}

// ---------------- 3x3 SAME conv, implicit GEMM, bf16 MFMA -----------------
// block = 2 rows x 128 co x 128 px, 8 waves (wco2 x wpx2 x wrow2), 512 thr.
// Wave = 64co x 64px, acc[2][2] (64 acc regs) -> total regs ~120 ->
// __launch_bounds__(512,4): 2 blocks/CU = 4 waves/SIMD TLP (the m97-style
// occupancy where pipe overlap actually happens).
// A-frags: global->REG per wave. Input: double-buffered LDS, plane padded to
// [p][4rows][136] = 1088 slots = 17 flat gl_lds ops (2/wave + wave0 extra).
// NO reg-staged tail. Counted vmcnt leaves only this-iter ops in flight.
template <int CIN, bool FUSE_DS>
__global__ __launch_bounds__(512, 4) void conv3x3(
    const unsigned short* __restrict__ src,  // [8][128][CIN/8][130][8]
    const unsigned short* __restrict__ wt,   // [cic][p][tap][co][8]
    const float* __restrict__ bias,          // [128]
    const unsigned short* __restrict__ zp,   // zeroed 8KB
    unsigned short* __restrict__ dst_bf16,   // [8][128][16][130][8]
    float* __restrict__ dst_f32,             // NCHW fp32 [8,128,128,128]
    const float* __restrict__ wds,           // [2,128] (FUSE_DS)
    const int* __restrict__ tar,             // [8,128,128] (FUSE_DS)
    float* __restrict__ ds,                  // [8,2,128,128] (FUSE_DS)
    float* __restrict__ amap) {              // [8,128,128] (FUSE_DS)
  constexpr int CPG = CIN / 8;
  constexpr int NC = CIN / 16;
  __shared__ unsigned short in_tile[2][1088 * 8];  // [buf][p][4rows][136][8]
  __shared__ float sb[128];
  __shared__ float w0s[128], w1s[128];
  __shared__ float sc[2 * 2 * 2 * 2 * 32];

  const int tid = threadIdx.x;
  // XCD-aware bijective swizzle: 512 blocks = 8 XCDs x 64 contiguous
  const int wg = (blockIdx.x & 7) * 64 + (blockIdx.x >> 3);
  const int b = wg >> 6;
  const int y0 = (wg & 63) * 2;
  const int lane = tid & 63, wave = tid >> 6;
  const int wco = wave & 1, wpx = (wave >> 1) & 1, wrow = wave >> 2;
  const int l31 = lane & 31, kh = lane >> 5;

  if (tid < 128) {
    sb[tid] = bias[tid];
    if constexpr (FUSE_DS) {
      w0s[tid] = wds[tid];
      w1s[tid] = wds[128 + tid];
    }
  }

  // ---- staging: flat table, op o covers slots [o*64, o*64+64).
  // slot s -> (p = s>=544, r = s-p*544, hy = r/136, hx = r-hy*136);
  // valid iff hx<130 && gy=y0-1+hy in [0,128); else zero page.
  const int nops = (wave == 0) ? 3 : 2;
  const unsigned short* gbase[3];
  int gstr[3];
  int lofs[3];  // LDS short-offset of op base in buffer 0
#pragma unroll
  for (int i = 0; i < 3; ++i) {
    const int o = (i < 2) ? (wave * 2 + i) : 16;
    const int s = o * 64 + lane;
    const int p = s >= 544;
    const int r = s - p * 544;
    const int hy = r / 136;
    const int hx = r - hy * 136;
    const int gy = y0 - 1 + hy;
    const bool ok = (hx < 130) && (gy >= 0) && (gy < 128);
    gbase[i] = ok ? src + ((size_t)((b * 128 + gy) * CPG) + p) * 1040 + hx * 8
                  : zp + lane * 8;
    gstr[i] = ok ? 2080 : 0;
    lofs[i] = o * 512;
  }

  f32x16 acc[2][2] = {};

  // prologue: stage chunk 0 into buf 0
#pragma unroll
  for (int i = 0; i < 3; ++i)
    if (i < nops) gl_lds16(gbase[i], &in_tile[0][(size_t)lofs[i]]);
  VMCNT0;
  BAR;

  // per-lane weight base: plane (kh) stride 9216 shorts, chunk stride 18432
  const unsigned short* wlane =
      wt + (size_t)kh * 9216 + (size_t)(wco * 64 + l31) * 8;

  for (int cic = 0; cic < NC; ++cic) {
    const int cur = cic & 1, nbuf = cur ^ 1;
    const bool more = (cic + 1 < NC);
    if (more) {
#pragma unroll
      for (int i = 0; i < 3; ++i)
        if (i < nops)
          gl_lds16(gbase[i] + (size_t)(cic + 1) * gstr[i],
                   &in_tile[nbuf][(size_t)lofs[i]]);
      SCHEDB;
      if (wave == 0) { VMCNT3; } else { VMCNT2; }  // drain chunk-k ops only
    } else {
      VMCNT0;
    }
    SCHEDB;
    BAR;  // B1: chunk k staged for all waves
    SCHEDB;

    // ---- compute chunk k (A-frags global->reg; TLP hides latency)
    const unsigned short* wl = wlane + (size_t)cic * 18432;
    const unsigned short* it = &in_tile[cur][0];
    const size_t ib = (size_t)kh * (544 * 8);
#pragma unroll
    for (int ky = 0; ky < 3; ++ky) {
      const int hy = ky + wrow;
      bf16x8 a0[3], a1[3];
#pragma unroll
      for (int t = 0; t < 3; ++t) {
        a0[t] = *(const bf16x8*)(wl + (ky * 3 + t) * 1024);
        a1[t] = *(const bf16x8*)(wl + (ky * 3 + t) * 1024 + 256);
      }
#pragma unroll
      for (int kx = 0; kx < 3; ++kx) {
        bf16x8 b0 = *(const bf16x8*)(&it[ib + (size_t)(hy * 136 + wpx * 64 + l31 + kx) * 8]);
        bf16x8 b1 = *(const bf16x8*)(&it[ib + (size_t)(hy * 136 + wpx * 64 + 32 + l31 + kx) * 8]);
        acc[0][0] = __builtin_amdgcn_mfma_f32_32x32x16_bf16(a0[kx], b0, acc[0][0], 0, 0, 0);
        acc[0][1] = __builtin_amdgcn_mfma_f32_32x32x16_bf16(a0[kx], b1, acc[0][1], 0, 0, 0);
        acc[1][0] = __builtin_amdgcn_mfma_f32_32x32x16_bf16(a1[kx], b0, acc[1][0], 0, 0, 0);
        acc[1][1] = __builtin_amdgcn_mfma_f32_32x32x16_bf16(a1[kx], b1, acc[1][1], 0, 0, 0);
      }
    }
    SCHEDB;
    LGKM0;  // my ds_reads retired
    BAR;    // B2: in_tile[cur] safe to overwrite next iteration
    SCHEDB;
  }

  // ---- epilogue. D: col(px)=lane&31, row(co)=(r&3)+8*(r>>2)+4*kh
  const int gyo = y0 + wrow;
  float pd[2][2] = {};  // [fp][cls] (FUSE_DS)
#pragma unroll
  for (int fc = 0; fc < 2; ++fc) {
#pragma unroll
    for (int fp = 0; fp < 2; ++fp) {
      const int px = wpx * 64 + fp * 32 + l31;
      if constexpr (!FUSE_DS) {
#pragma unroll
        for (int rg = 0; rg < 4; ++rg) {
          const int co0 = wco * 64 + fc * 32 + rg * 8 + kh * 4;
          unsigned short pk[4];
#pragma unroll
          for (int q = 0; q < 4; ++q) {
            float v = acc[fc][fp][rg * 4 + q] + sb[co0 + q];
            v = v > 0.f ? v : 0.01f * v;
            pk[q] = f2bf(v);
          }
          uint2 o;
          o.x = (unsigned)pk[0] | ((unsigned)pk[1] << 16);
          o.y = (unsigned)pk[2] | ((unsigned)pk[3] << 16);
          *(uint2*)(&dst_bf16[(((long)(b * 128 + gyo) * 16 + (co0 >> 3)) * 130 + px + 1) * 8 +
                              kh * 4]) = o;
        }
      } else {
#pragma unroll
        for (int rg = 0; rg < 4; ++rg) {
          const int co0 = wco * 64 + fc * 32 + rg * 8 + kh * 4;
          float4 wv0 = *(const float4*)(&w0s[co0]);
          float4 wv1 = *(const float4*)(&w1s[co0]);
#pragma unroll
          for (int q = 0; q < 4; ++q) {
            float v = acc[fc][fp][rg * 4 + q] + sb[co0 + q];
            v = v > 0.f ? v : 0.01f * v;
            dst_f32[((long)(b * 128 + co0 + q) << 14) + (gyo << 7) + px] = v;
            float wq0 = (q == 0) ? wv0.x : (q == 1) ? wv0.y : (q == 2) ? wv0.z : wv0.w;
            float wq1 = (q == 0) ? wv1.x : (q == 1) ? wv1.y : (q == 2) ? wv1.z : wv1.w;
            pd[fp][0] += wq0 * v;
            pd[fp][1] += wq1 * v;
          }
        }
      }
    }
  }

  if constexpr (!FUSE_DS) {  // zero px 0,129 of this block's 2 rows, all cig
    if (tid < 64) {
      int row = tid >> 5, g = (tid >> 1) & 15;
      long col = (tid & 1) * 129L;
      *(uint4*)(&dst_bf16[(((long)(b * 128 + y0 + row) * 16 + g) * 130 + col) * 8]) =
          make_uint4(0, 0, 0, 0);
    }
  } else {
    // kh shuffle sums the two co-subsets (same px), then wco pair via LDS
#pragma unroll
    for (int fp = 0; fp < 2; ++fp)
#pragma unroll
      for (int c = 0; c < 2; ++c)
        pd[fp][c] += __shfl_xor(pd[fp][c], 32, 64);
    if (wco == 1 && kh == 0) {
#pragma unroll
      for (int fp = 0; fp < 2; ++fp)
#pragma unroll
        for (int c = 0; c < 2; ++c)
          sc[((((wrow * 2 + wpx) * 2 + fp) * 2 + c)) * 32 + l31] = pd[fp][c];
    }
    __syncthreads();
    if (wco == 0 && kh == 0) {
      const int* tb = tar + (long)b * 16384;
#pragma unroll
      for (int fp = 0; fp < 2; ++fp) {
        const int px = wpx * 64 + fp * 32 + l31;
        float a0f = pd[fp][0] + sc[((((wrow * 2 + wpx) * 2 + fp) * 2 + 0)) * 32 + l31];
        float a1f = pd[fp][1] + sc[((((wrow * 2 + wpx) * 2 + fp) * 2 + 1)) * 32 + l31];
        ds[((long)b * 2) * 16384 + (gyo << 7) + px] = a0f;
        ds[((long)b * 2 + 1) * 16384 + (gyo << 7) + px] = a1f;
        float m = fmaxf(a0f, a1f);
        float e0 = expf(a0f - m), e1 = expf(a1f - m);
        float s = e0 + e1;
        float p0f = e0 / s, p1f = e1 / s;
        float ent = -(p0f * log2f(p0f + 1e-6f) + p1f * log2f(p1f + 1e-6f));
        float un = ent >= 0.001f ? 1.f : 0.f;
        float pro = 1.f;
        if (gyo > 0 && gyo < 127 && px > 0 && px < 127) {
          int c = tb[(gyo << 7) + px];
          if (c != 0) {
            int nb2 = tb[((gyo - 1) << 7) + px] + tb[((gyo + 1) << 7) + px] +
                      tb[(gyo << 7) + px - 1] + tb[(gyo << 7) + px + 1];
            if (4 * c != nb2) pro = 0.f;
          }
        }
        amap[((long)(b * 128 + gyo) << 7) + px] = un * pro;
      }
    }
  }
}

extern "C" void kernel_launch(void* const* d_in, const int* in_sizes, int n_in,
                              void* d_out, int out_size, void* d_ws, size_t ws_size,
                              hipStream_t stream) {
  const float* x    = (const float*)d_in[0];
  const float* skip = (const float*)d_in[1];
  const int*   tar  = (const int*)d_in[2];
  const float* W1   = (const float*)d_in[3];
  const float* b1   = (const float*)d_in[4];
  const float* W2   = (const float*)d_in[5];
  const float* b2   = (const float*)d_in[6];
  const float* Wds  = (const float*)d_in[7];

  float* out_h  = (float*)d_out;            // 16777216 f32 (h, NCHW)
  float* out_ds = out_h + 16777216;         // 262144 f32
  float* out_am = out_ds + 262144;          // 131072 f32

  // ws: W1b | W2b | zp | (1MB) h1  [8][128][16][130][8] bf16 (34.1MB)
  unsigned short* W1b = (unsigned short*)d_ws;
  unsigned short* W2b = W1b + 294912;
  unsigned short* zp  = W2b + 147456;
  unsigned short* h1  = (unsigned short*)((char*)d_ws + (1u << 20));

  // h0: [8][128][32][130][8] bf16 = 68.2MB, lives in d_out (68.7MB);
  // fully dead before conv2 overwrites d_out (h/ds/amap regions).
  unsigned short* h0 = (unsigned short*)d_out;

  convert_weights<<<1729, 256, 0, stream>>>(W1, W2, W1b, W2b, zp);
  transpose_to_bf16<<<2048, 256, 0, stream>>>(x, skip, h0);
  conv3x3<256, false><<<512, 512, 0, stream>>>(h0, W1b, b1, zp, h1, nullptr,
                                               nullptr, nullptr, nullptr, nullptr);
  conv3x3<128, true><<<512, 512, 0, stream>>>(h1, W2b, b2, zp, nullptr, out_h,
                                              Wds, tar, out_ds, out_am);
}

// Round 15
// 147.288 us; speedup vs baseline: 1.2104x; 1.2104x over previous
//
#include <hip/hip_runtime.h>

typedef float f32x16 __attribute__((ext_vector_type(16)));
typedef short bf16x8 __attribute__((ext_vector_type(8)));
typedef unsigned int u32;

static __device__ __forceinline__ unsigned short f2bf(float f) {
  union { float f; unsigned int u; } v;
  v.f = f;
  return (unsigned short)((v.u + 0x7FFFu + ((v.u >> 16) & 1u)) >> 16);
}

// async 16B global->LDS (DMA). LDS dest = wave-uniform base + lane*16.
static __device__ __forceinline__ void gl_lds16(const unsigned short* g,
                                                unsigned short* l) {
  __builtin_amdgcn_global_load_lds(
      (const __attribute__((address_space(1))) u32*)g,
      (__attribute__((address_space(3))) u32*)l, 16, 0, 0);
}

#define VMCNT0 asm volatile("s_waitcnt vmcnt(0)" ::: "memory")
#define LGKM0 asm volatile("s_waitcnt lgkmcnt(0)" ::: "memory")
#define BAR __builtin_amdgcn_s_barrier()
#define SCHEDB __builtin_amdgcn_sched_barrier(0)
#define PRIO1 __builtin_amdgcn_s_setprio(1)
#define PRIO0 __builtin_amdgcn_s_setprio(0)

// ---- weights: OIHW fp32 -> [cic][p][tap][co][8ci] bf16 (contiguous 36KB
// per-chunk slab, linear order == LDS layout); + zero page.
__global__ __launch_bounds__(256) void convert_weights(
    const float* __restrict__ W1, const float* __restrict__ W2,
    unsigned short* __restrict__ W1b, unsigned short* __restrict__ W2b,
    unsigned short* __restrict__ zp) {
  if (blockIdx.x == 1728) {
    uint4* z = (uint4*)zp;
    z[threadIdx.x] = make_uint4(0, 0, 0, 0);
    z[256 + threadIdx.x] = make_uint4(0, 0, 0, 0);
    return;
  }
  int i = blockIdx.x * 256 + threadIdx.x;
  if (i < 294912) {
    int e = i & 7, co = (i >> 3) & 127, r = i >> 10;  // r=(cic*2+p)*9+tap
    int tap = r % 9, pc = r / 9;
    int ci = (pc >> 1) * 16 + (pc & 1) * 8 + e;
    W1b[i] = f2bf(W1[(co * 256 + ci) * 9 + tap]);
  } else {
    int j = i - 294912;
    if (j < 147456) {
      int e = j & 7, co = (j >> 3) & 127, r = j >> 10;
      int tap = r % 9, pc = r / 9;
      int ci = (pc >> 1) * 16 + (pc & 1) * 8 + e;
      W2b[j] = f2bf(W2[(co * 128 + ci) * 9 + tap]);
    }
  }
}

// -- NCHW fp32 -> padded plane-major bf16 [8][128][32 cig][130 px][8 ci] ----
__global__ __launch_bounds__(256) void transpose_to_bf16(
    const float* __restrict__ x, const float* __restrict__ skip,
    unsigned short* __restrict__ dst) {
  int bid = blockIdx.x;
  const float* src = (bid < 1024) ? x : skip;
  int cigb = (bid < 1024) ? 0 : 16;
  int row = bid & 1023;  // b*128+y
  int b = row >> 7, y = row & 127;
  const float* s = src + (long)b * 128 * 16384 + (long)y * 128;
  for (int it = 0; it < 8; ++it) {
    int u = it * 256 + (int)threadIdx.x;
    int cig = u >> 7, px = u & 127;
    unsigned short pk[8];
#pragma unroll
    for (int e = 0; e < 8; ++e)
      pk[e] = f2bf(s[(long)(cig * 8 + e) * 16384 + px]);
    uint4 vv;
    vv.x = (unsigned)pk[0] | ((unsigned)pk[1] << 16);
    vv.y = (unsigned)pk[2] | ((unsigned)pk[3] << 16);
    vv.z = (unsigned)pk[4] | ((unsigned)pk[5] << 16);
    vv.w = (unsigned)pk[6] | ((unsigned)pk[7] << 16);
    *(uint4*)(&dst[(((long)row * 32 + cigb + cig) * 130 + px + 1) * 8]) = vv;
  }
  if (cigb == 0 && threadIdx.x < 64) {  // zero px 0,129 for all 32 cig
    int g = threadIdx.x >> 1;
    long col = (threadIdx.x & 1) * 129L;
    *(uint4*)(&dst[(((long)row * 32 + g) * 130 + col) * 8]) = make_uint4(0, 0, 0, 0);
  }
}

// ---------------- 3x3 SAME conv, implicit GEMM, bf16 MFMA -----------------
// block = 4 rows x 128 co x 128 px, 8 waves (wco 2 x wrow 4), 512 thr.
// R10 staging skeleton (fully double-buffered, flat 64-op table, gl_lds) +
// NEW: chunk split into 3 PHASES (3 taps each) with a barrier per phase,
// staging spread 4/4/0 across phases (loads in flight across barriers, T4),
// setprio(1) around each phase's MFMA cluster (T5), 2-deep tap register
// pipeline (R11). Single vmcnt(0) at chunk end (newest op >=1 phase old).
template <int CIN, bool FUSE_DS>
__global__ __launch_bounds__(512, 2) void conv3x3(
    const unsigned short* __restrict__ src,  // [8][128][CIN/8][130][8]
    const unsigned short* __restrict__ wt,   // [cic][p][tap][co][8]
    const float* __restrict__ bias,          // [128]
    const unsigned short* __restrict__ zp,   // zeroed 8KB
    unsigned short* __restrict__ dst_bf16,   // [8][128][16][130][8]
    float* __restrict__ dst_f32,             // NCHW fp32 [8,128,128,128]
    const float* __restrict__ wds,           // [2,128] (FUSE_DS)
    const int* __restrict__ tar,             // [8,128,128] (FUSE_DS)
    float* __restrict__ ds,                  // [8,2,128,128] (FUSE_DS)
    float* __restrict__ amap) {              // [8,128,128] (FUSE_DS)
  constexpr int CPG = CIN / 8;
  constexpr int NC = CIN / 16;
  __shared__ unsigned short in_tile[2][1664 * 8];  // 2 x 26 KB
  __shared__ unsigned short wt_tile[2][2304 * 8];  // 2 x 36.9 KB
  __shared__ unsigned short scr[64 * 8];           // dummy-op sink, 1 KB
  __shared__ float sb[128];
  __shared__ float w0s[128], w1s[128];
  __shared__ float sc[4 * 4 * 2 * 32];

  const int tid = threadIdx.x;
  // XCD-aware bijective swizzle: 256 blocks = 8 XCDs x 32 contiguous
  const int wg = (blockIdx.x & 7) * 32 + (blockIdx.x >> 3);
  const int b = wg >> 5;
  const int y0 = (wg & 31) * 4;
  const int lane = tid & 63, wave = tid >> 6;
  const int wco = wave & 1, wrow = wave >> 1;
  const int l31 = lane & 31, kh = lane >> 5;

  if (tid < 128) {
    sb[tid] = bias[tid];
    if constexpr (FUSE_DS) {
      w0s[tid] = wds[tid];
      w1s[tid] = wds[128 + tid];
    }
  }

  // ---- flat op table: ops 0..35 = wt slab, 36..61 = input, 62..63 dummy
  const unsigned short* gb[8];
  unsigned short* ld0[8];
  int gst[8];
  int lst[8];
#pragma unroll
  for (int i = 0; i < 8; ++i) {
    const int o = wave * 8 + i;
    if (o < 36) {
      gb[i] = wt + o * 512 + lane * 8;
      gst[i] = 18432;
      ld0[i] = &wt_tile[0][(size_t)o * 512];
      lst[i] = 18432;
    } else if (o < 62) {
      const int q = o - 36;
      const int p = q / 13, j = q - p * 13;
      const int s = j * 64 + lane;
      const int hy = s / 130, hx = s - hy * 130;
      const int gy = y0 - 1 + hy;
      const bool ok = (s < 780) && (gy >= 0) && (gy < 128);
      gb[i] = ok ? src + ((size_t)((b * 128 + gy) * CPG) + p) * 1040 + hx * 8
                 : zp + lane * 8;
      gst[i] = ok ? 2080 : 0;
      ld0[i] = &in_tile[0][(size_t)(p * 832 + j * 64) * 8];
      lst[i] = 1664 * 8;
    } else {
      gb[i] = zp + lane * 8;
      gst[i] = 0;
      ld0[i] = &scr[0];
      lst[i] = 0;
    }
  }

  f32x16 acc[2][4] = {};

  // prologue: stage chunk 0 into buf 0
#pragma unroll
  for (int i = 0; i < 8; ++i) gl_lds16(gb[i], ld0[i]);
  VMCNT0;
  LGKM0;
  BAR;
  SCHEDB;

  for (int cic = 0; cic < NC; ++cic) {
    const int cur = cic & 1;
    const int nbuf = cur ^ 1;
    const bool more = (cic + 1 < NC);

    const unsigned short* it = &in_tile[cur][0];
    const unsigned short* wl = &wt_tile[cur][0];
    const size_t ib = (size_t)kh * (832 * 8);
    const size_t wb = (size_t)kh * 9216;

    bf16x8 xa0, xa1, xb0, xb1, xb2, xb3;  // even-tap set
    bf16x8 ya0, ya1, yb0, yb1, yb2, yb3;  // odd-tap set

#define LD_TAP(T, A0, A1, B0, B1, B2, B3)                                      \
  {                                                                            \
    constexpr int ky_ = (T) / 3, kx_ = (T) % 3;                                \
    const int hy_ = ky_ + wrow;                                                \
    A0 = *(const bf16x8*)(&wl[wb + (size_t)((T)*128 + wco * 64 + l31) * 8]);   \
    A1 = *(const bf16x8*)(&wl[wb + (size_t)((T)*128 + wco * 64 + 32 + l31) * 8]); \
    B0 = *(const bf16x8*)(&it[ib + (size_t)(hy_ * 130 + l31 + kx_) * 8]);      \
    B1 = *(const bf16x8*)(&it[ib + (size_t)(hy_ * 130 + 32 + l31 + kx_) * 8]); \
    B2 = *(const bf16x8*)(&it[ib + (size_t)(hy_ * 130 + 64 + l31 + kx_) * 8]); \
    B3 = *(const bf16x8*)(&it[ib + (size_t)(hy_ * 130 + 96 + l31 + kx_) * 8]); \
  }

#define MFMA_TAP(A0, A1, B0, B1, B2, B3)                                       \
  {                                                                            \
    acc[0][0] = __builtin_amdgcn_mfma_f32_32x32x16_bf16(A0, B0, acc[0][0], 0, 0, 0); \
    acc[0][1] = __builtin_amdgcn_mfma_f32_32x32x16_bf16(A0, B1, acc[0][1], 0, 0, 0); \
    acc[0][2] = __builtin_amdgcn_mfma_f32_32x32x16_bf16(A0, B2, acc[0][2], 0, 0, 0); \
    acc[0][3] = __builtin_amdgcn_mfma_f32_32x32x16_bf16(A0, B3, acc[0][3], 0, 0, 0); \
    acc[1][0] = __builtin_amdgcn_mfma_f32_32x32x16_bf16(A1, B0, acc[1][0], 0, 0, 0); \
    acc[1][1] = __builtin_amdgcn_mfma_f32_32x32x16_bf16(A1, B1, acc[1][1], 0, 0, 0); \
    acc[1][2] = __builtin_amdgcn_mfma_f32_32x32x16_bf16(A1, B2, acc[1][2], 0, 0, 0); \
    acc[1][3] = __builtin_amdgcn_mfma_f32_32x32x16_bf16(A1, B3, acc[1][3], 0, 0, 0); \
  }

    // preload taps 0,1 (buf[cur] is ready: chunk-end VMCNT0+BAR behind us)
    LD_TAP(0, xa0, xa1, xb0, xb1, xb2, xb3);
    LD_TAP(1, ya0, ya1, yb0, yb1, yb2, yb3);
    SCHEDB;

    // ---- PHASE 0: taps 0-2; stage ops 0-3 for chunk k+1
    if (more) {
#pragma unroll
      for (int i = 0; i < 4; ++i)
        gl_lds16(gb[i] + (size_t)(cic + 1) * gst[i],
                 ld0[i] + (size_t)nbuf * lst[i]);
    }
    SCHEDB;
    BAR;
    PRIO1;
    MFMA_TAP(xa0, xa1, xb0, xb1, xb2, xb3);   // tap 0
    LD_TAP(2, xa0, xa1, xb0, xb1, xb2, xb3);
    SCHEDB;
    MFMA_TAP(ya0, ya1, yb0, yb1, yb2, yb3);   // tap 1
    LD_TAP(3, ya0, ya1, yb0, yb1, yb2, yb3);
    SCHEDB;
    MFMA_TAP(xa0, xa1, xb0, xb1, xb2, xb3);   // tap 2
    LD_TAP(4, xa0, xa1, xb0, xb1, xb2, xb3);
    SCHEDB;
    PRIO0;

    // ---- PHASE 1: taps 3-5; stage ops 4-7 for chunk k+1
    if (more) {
#pragma unroll
      for (int i = 4; i < 8; ++i)
        gl_lds16(gb[i] + (size_t)(cic + 1) * gst[i],
                 ld0[i] + (size_t)nbuf * lst[i]);
    }
    SCHEDB;
    BAR;
    PRIO1;
    MFMA_TAP(ya0, ya1, yb0, yb1, yb2, yb3);   // tap 3
    LD_TAP(5, ya0, ya1, yb0, yb1, yb2, yb3);
    SCHEDB;
    MFMA_TAP(xa0, xa1, xb0, xb1, xb2, xb3);   // tap 4
    LD_TAP(6, xa0, xa1, xb0, xb1, xb2, xb3);
    SCHEDB;
    MFMA_TAP(ya0, ya1, yb0, yb1, yb2, yb3);   // tap 5
    LD_TAP(7, ya0, ya1, yb0, yb1, yb2, yb3);
    SCHEDB;
    PRIO0;

    // ---- PHASE 2: taps 6-8; no staging
    BAR;
    PRIO1;
    MFMA_TAP(xa0, xa1, xb0, xb1, xb2, xb3);   // tap 6
    LD_TAP(8, xa0, xa1, xb0, xb1, xb2, xb3);
    SCHEDB;
    MFMA_TAP(ya0, ya1, yb0, yb1, yb2, yb3);   // tap 7
    SCHEDB;
    MFMA_TAP(xa0, xa1, xb0, xb1, xb2, xb3);   // tap 8
    PRIO0;
#undef LD_TAP
#undef MFMA_TAP

    SCHEDB;
    LGKM0;   // my ds_reads retired
    VMCNT0;  // chunk-(k+1) staging landed (newest op issued 1+ phase ago)
    BAR;     // chunk end: buffers safe to swap
    SCHEDB;
  }

  // ---- epilogue. D: col(px)=lane&31, row(co)=(r&3)+8*(r>>2)+4*kh
  const int gyo = y0 + wrow;
  float pd[4][2] = {};  // [fp][cls] (FUSE_DS)
#pragma unroll
  for (int fc = 0; fc < 2; ++fc) {
#pragma unroll
    for (int fp = 0; fp < 4; ++fp) {
      const int px = fp * 32 + l31;
      if constexpr (!FUSE_DS) {
#pragma unroll
        for (int rg = 0; rg < 4; ++rg) {
          const int co0 = wco * 64 + fc * 32 + rg * 8 + kh * 4;
          unsigned short pk[4];
#pragma unroll
          for (int q = 0; q < 4; ++q) {
            float v = acc[fc][fp][rg * 4 + q] + sb[co0 + q];
            v = v > 0.f ? v : 0.01f * v;
            pk[q] = f2bf(v);
          }
          uint2 o;
          o.x = (unsigned)pk[0] | ((unsigned)pk[1] << 16);
          o.y = (unsigned)pk[2] | ((unsigned)pk[3] << 16);
          *(uint2*)(&dst_bf16[(((long)(b * 128 + gyo) * 16 + (co0 >> 3)) * 130 + px + 1) * 8 +
                              kh * 4]) = o;
        }
      } else {
#pragma unroll
        for (int rg = 0; rg < 4; ++rg) {
          const int co0 = wco * 64 + fc * 32 + rg * 8 + kh * 4;
          float4 wv0 = *(const float4*)(&w0s[co0]);
          float4 wv1 = *(const float4*)(&w1s[co0]);
#pragma unroll
          for (int q = 0; q < 4; ++q) {
            float v = acc[fc][fp][rg * 4 + q] + sb[co0 + q];
            v = v > 0.f ? v : 0.01f * v;
            dst_f32[((long)(b * 128 + co0 + q) << 14) + (gyo << 7) + px] = v;
            float wq0 = (q == 0) ? wv0.x : (q == 1) ? wv0.y : (q == 2) ? wv0.z : wv0.w;
            float wq1 = (q == 0) ? wv1.x : (q == 1) ? wv1.y : (q == 2) ? wv1.z : wv1.w;
            pd[fp][0] += wq0 * v;
            pd[fp][1] += wq1 * v;
          }
        }
      }
    }
  }

  if constexpr (!FUSE_DS) {  // zero px 0,129 of this block's 4 rows, all cig
    if (tid < 128) {
      int row = tid >> 5, g = (tid >> 1) & 15;
      long col = (tid & 1) * 129L;
      *(uint4*)(&dst_bf16[(((long)(b * 128 + y0 + row) * 16 + g) * 130 + col) * 8]) =
          make_uint4(0, 0, 0, 0);
    }
  } else {
    // reduce kh (lane^32), then wco pairs via LDS scratch
#pragma unroll
    for (int fp = 0; fp < 4; ++fp)
#pragma unroll
      for (int c = 0; c < 2; ++c)
        pd[fp][c] += __shfl_xor(pd[fp][c], 32, 64);
    if (wco == 1 && kh == 0) {
#pragma unroll
      for (int fp = 0; fp < 4; ++fp)
#pragma unroll
        for (int c = 0; c < 2; ++c)
          sc[((wrow * 4 + fp) * 2 + c) * 32 + l31] = pd[fp][c];
    }
    __syncthreads();
    if (wco == 0 && kh == 0) {
      const int* tb = tar + (long)b * 16384;
#pragma unroll
      for (int fp = 0; fp < 4; ++fp) {
        const int px = fp * 32 + l31;
        float a0 = pd[fp][0] + sc[((wrow * 4 + fp) * 2 + 0) * 32 + l31];
        float a1 = pd[fp][1] + sc[((wrow * 4 + fp) * 2 + 1) * 32 + l31];
        ds[((long)b * 2) * 16384 + (gyo << 7) + px] = a0;
        ds[((long)b * 2 + 1) * 16384 + (gyo << 7) + px] = a1;
        float m = fmaxf(a0, a1);
        float e0 = expf(a0 - m), e1 = expf(a1 - m);
        float s = e0 + e1;
        float p0f = e0 / s, p1f = e1 / s;
        float ent = -(p0f * log2f(p0f + 1e-6f) + p1f * log2f(p1f + 1e-6f));
        float un = ent >= 0.001f ? 1.f : 0.f;
        float pro = 1.f;
        if (gyo > 0 && gyo < 127 && px > 0 && px < 127) {
          int c = tb[(gyo << 7) + px];
          if (c != 0) {
            int nb2 = tb[((gyo - 1) << 7) + px] + tb[((gyo + 1) << 7) + px] +
                      tb[(gyo << 7) + px - 1] + tb[(gyo << 7) + px + 1];
            if (4 * c != nb2) pro = 0.f;
          }
        }
        amap[((long)(b * 128 + gyo) << 7) + px] = un * pro;
      }
    }
  }
}

extern "C" void kernel_launch(void* const* d_in, const int* in_sizes, int n_in,
                              void* d_out, int out_size, void* d_ws, size_t ws_size,
                              hipStream_t stream) {
  const float* x    = (const float*)d_in[0];
  const float* skip = (const float*)d_in[1];
  const int*   tar  = (const int*)d_in[2];
  const float* W1   = (const float*)d_in[3];
  const float* b1   = (const float*)d_in[4];
  const float* W2   = (const float*)d_in[5];
  const float* b2   = (const float*)d_in[6];
  const float* Wds  = (const float*)d_in[7];

  float* out_h  = (float*)d_out;            // 16777216 f32 (h, NCHW)
  float* out_ds = out_h + 16777216;         // 262144 f32
  float* out_am = out_ds + 262144;          // 131072 f32

  // ws: W1b | W2b | zp | (1MB) h1  [8][128][16][130][8] bf16 (34.1MB)
  unsigned short* W1b = (unsigned short*)d_ws;
  unsigned short* W2b = W1b + 294912;
  unsigned short* zp  = W2b + 147456;
  unsigned short* h1  = (unsigned short*)((char*)d_ws + (1u << 20));

  // h0: [8][128][32][130][8] bf16 = 68.2MB, lives in d_out (68.7MB);
  // fully dead before conv2 overwrites d_out (h/ds/amap regions).
  unsigned short* h0 = (unsigned short*)d_out;

  convert_weights<<<1729, 256, 0, stream>>>(W1, W2, W1b, W2b, zp);
  transpose_to_bf16<<<2048, 256, 0, stream>>>(x, skip, h0);
  conv3x3<256, false><<<256, 512, 0, stream>>>(h0, W1b, b1, zp, h1, nullptr,
                                               nullptr, nullptr, nullptr, nullptr);
  conv3x3<128, true><<<256, 512, 0, stream>>>(h1, W2b, b2, zp, nullptr, out_h,
                                              Wds, tar, out_ds, out_am);
}

// Round 16
// 142.812 us; speedup vs baseline: 1.2484x; 1.0313x over previous
//
#include <hip/hip_runtime.h>

typedef float f32x16 __attribute__((ext_vector_type(16)));
typedef short bf16x8 __attribute__((ext_vector_type(8)));
typedef unsigned int u32;

static __device__ __forceinline__ unsigned short f2bf(float f) {
  union { float f; unsigned int u; } v;
  v.f = f;
  return (unsigned short)((v.u + 0x7FFFu + ((v.u >> 16) & 1u)) >> 16);
}

// async 16B global->LDS (DMA). LDS dest = wave-uniform base + lane*16.
static __device__ __forceinline__ void gl_lds16(const unsigned short* g,
                                                unsigned short* l) {
  __builtin_amdgcn_global_load_lds(
      (const __attribute__((address_space(1))) u32*)g,
      (__attribute__((address_space(3))) u32*)l, 16, 0, 0);
}

#define VMCNT0 asm volatile("s_waitcnt vmcnt(0)" ::: "memory")
#define LGKM0 asm volatile("s_waitcnt lgkmcnt(0)" ::: "memory")
#define BAR __builtin_amdgcn_s_barrier()
#define SCHEDB __builtin_amdgcn_sched_barrier(0)
#define PRIO1 __builtin_amdgcn_s_setprio(1)
#define PRIO0 __builtin_amdgcn_s_setprio(0)

// ---- prep: merged transpose (blocks 0..2047) + weight convert (2048..3776)
// transpose: NCHW fp32 -> padded plane-major bf16 [8][128][32 cig][130 px][8]
// weights:  OIHW fp32 -> [cic][p][tap][co][8ci] bf16 slabs; + zero page.
__global__ __launch_bounds__(256) void prep(
    const float* __restrict__ x, const float* __restrict__ skip,
    const float* __restrict__ W1, const float* __restrict__ W2,
    unsigned short* __restrict__ dst, unsigned short* __restrict__ W1b,
    unsigned short* __restrict__ W2b, unsigned short* __restrict__ zp) {
  const int bid = blockIdx.x;
  if (bid >= 2048) {
    const int cb = bid - 2048;
    if (cb == 1728) {  // zero the 8KB zero page
      uint4* z = (uint4*)zp;
      z[threadIdx.x] = make_uint4(0, 0, 0, 0);
      z[256 + threadIdx.x] = make_uint4(0, 0, 0, 0);
      return;
    }
    int i = cb * 256 + (int)threadIdx.x;
    if (i < 294912) {
      int e = i & 7, co = (i >> 3) & 127, r = i >> 10;  // r=(cic*2+p)*9+tap
      int tap = r % 9, pc = r / 9;
      int ci = (pc >> 1) * 16 + (pc & 1) * 8 + e;
      W1b[i] = f2bf(W1[(co * 256 + ci) * 9 + tap]);
    } else {
      int j = i - 294912;
      if (j < 147456) {
        int e = j & 7, co = (j >> 3) & 127, r = j >> 10;
        int tap = r % 9, pc = r / 9;
        int ci = (pc >> 1) * 16 + (pc & 1) * 8 + e;
        W2b[j] = f2bf(W2[(co * 128 + ci) * 9 + tap]);
      }
    }
    return;
  }
  const float* src = (bid < 1024) ? x : skip;
  const int cigb = (bid < 1024) ? 0 : 16;
  const int row = bid & 1023;  // b*128+y
  const int b = row >> 7, y = row & 127;
  const float* s = src + (long)b * 128 * 16384 + (long)y * 128;
  for (int it = 0; it < 8; ++it) {
    int u = it * 256 + (int)threadIdx.x;
    int cig = u >> 7, px = u & 127;
    unsigned short pk[8];
#pragma unroll
    for (int e = 0; e < 8; ++e)
      pk[e] = f2bf(s[(long)(cig * 8 + e) * 16384 + px]);
    uint4 vv;
    vv.x = (unsigned)pk[0] | ((unsigned)pk[1] << 16);
    vv.y = (unsigned)pk[2] | ((unsigned)pk[3] << 16);
    vv.z = (unsigned)pk[4] | ((unsigned)pk[5] << 16);
    vv.w = (unsigned)pk[6] | ((unsigned)pk[7] << 16);
    *(uint4*)(&dst[(((long)row * 32 + cigb + cig) * 130 + px + 1) * 8]) = vv;
  }
  if (cigb == 0 && threadIdx.x < 64) {  // zero px 0,129 for all 32 cig
    int g = threadIdx.x >> 1;
    long col = (threadIdx.x & 1) * 129L;
    *(uint4*)(&dst[(((long)row * 32 + g) * 130 + col) * 8]) = make_uint4(0, 0, 0, 0);
  }
}

// ---------------- 3x3 SAME conv, implicit GEMM, bf16 MFMA -----------------
// block = 4 rows x 128 co x 128 px, 8 waves (wco 2 x wrow 4), 512 thr.
// Fully double-buffered staging (flat 64-op table, gl_lds). Chunk = 3 phases
// (3 taps each) with a barrier per phase; ALL 8 stage-ops issued in phase 0
// (by the chunk-end vmcnt(0) they are ~2 phases old -> drain free, T4);
// setprio(1) tight around each 8-MFMA cluster only (T5, m201-faithful);
// 2-deep tap register pipeline.
template <int CIN, bool FUSE_DS>
__global__ __launch_bounds__(512, 2) void conv3x3(
    const unsigned short* __restrict__ src,  // [8][128][CIN/8][130][8]
    const unsigned short* __restrict__ wt,   // [cic][p][tap][co][8]
    const float* __restrict__ bias,          // [128]
    const unsigned short* __restrict__ zp,   // zeroed 8KB
    unsigned short* __restrict__ dst_bf16,   // [8][128][16][130][8]
    float* __restrict__ dst_f32,             // NCHW fp32 [8,128,128,128]
    const float* __restrict__ wds,           // [2,128] (FUSE_DS)
    const int* __restrict__ tar,             // [8,128,128] (FUSE_DS)
    float* __restrict__ ds,                  // [8,2,128,128] (FUSE_DS)
    float* __restrict__ amap) {              // [8,128,128] (FUSE_DS)
  constexpr int CPG = CIN / 8;
  constexpr int NC = CIN / 16;
  __shared__ unsigned short in_tile[2][1664 * 8];  // 2 x 26 KB
  __shared__ unsigned short wt_tile[2][2304 * 8];  // 2 x 36.9 KB
  __shared__ unsigned short scr[64 * 8];           // dummy-op sink, 1 KB
  __shared__ float sb[128];
  __shared__ float w0s[128], w1s[128];
  __shared__ float sc[4 * 4 * 2 * 32];

  const int tid = threadIdx.x;
  // XCD-aware bijective swizzle: 256 blocks = 8 XCDs x 32 contiguous
  const int wg = (blockIdx.x & 7) * 32 + (blockIdx.x >> 3);
  const int b = wg >> 5;
  const int y0 = (wg & 31) * 4;
  const int lane = tid & 63, wave = tid >> 6;
  const int wco = wave & 1, wrow = wave >> 1;
  const int l31 = lane & 31, kh = lane >> 5;

  if (tid < 128) {
    sb[tid] = bias[tid];
    if constexpr (FUSE_DS) {
      w0s[tid] = wds[tid];
      w1s[tid] = wds[128 + tid];
    }
  }

  // ---- flat op table: ops 0..35 = wt slab, 36..61 = input, 62..63 dummy
  const unsigned short* gb[8];
  unsigned short* ld0[8];
  int gst[8];
  int lst[8];
#pragma unroll
  for (int i = 0; i < 8; ++i) {
    const int o = wave * 8 + i;
    if (o < 36) {
      gb[i] = wt + o * 512 + lane * 8;
      gst[i] = 18432;
      ld0[i] = &wt_tile[0][(size_t)o * 512];
      lst[i] = 18432;
    } else if (o < 62) {
      const int q = o - 36;
      const int p = q / 13, j = q - p * 13;
      const int s = j * 64 + lane;
      const int hy = s / 130, hx = s - hy * 130;
      const int gy = y0 - 1 + hy;
      const bool ok = (s < 780) && (gy >= 0) && (gy < 128);
      gb[i] = ok ? src + ((size_t)((b * 128 + gy) * CPG) + p) * 1040 + hx * 8
                 : zp + lane * 8;
      gst[i] = ok ? 2080 : 0;
      ld0[i] = &in_tile[0][(size_t)(p * 832 + j * 64) * 8];
      lst[i] = 1664 * 8;
    } else {
      gb[i] = zp + lane * 8;
      gst[i] = 0;
      ld0[i] = &scr[0];
      lst[i] = 0;
    }
  }

  f32x16 acc[2][4] = {};

  // prologue: stage chunk 0 into buf 0
#pragma unroll
  for (int i = 0; i < 8; ++i) gl_lds16(gb[i], ld0[i]);
  VMCNT0;
  LGKM0;
  BAR;
  SCHEDB;

  for (int cic = 0; cic < NC; ++cic) {
    const int cur = cic & 1;
    const int nbuf = cur ^ 1;
    const bool more = (cic + 1 < NC);

    const unsigned short* it = &in_tile[cur][0];
    const unsigned short* wl = &wt_tile[cur][0];
    const size_t ib = (size_t)kh * (832 * 8);
    const size_t wb = (size_t)kh * 9216;

    bf16x8 xa0, xa1, xb0, xb1, xb2, xb3;  // even-tap set
    bf16x8 ya0, ya1, yb0, yb1, yb2, yb3;  // odd-tap set

#define LD_TAP(T, A0, A1, B0, B1, B2, B3)                                      \
  {                                                                            \
    constexpr int ky_ = (T) / 3, kx_ = (T) % 3;                                \
    const int hy_ = ky_ + wrow;                                                \
    A0 = *(const bf16x8*)(&wl[wb + (size_t)((T)*128 + wco * 64 + l31) * 8]);   \
    A1 = *(const bf16x8*)(&wl[wb + (size_t)((T)*128 + wco * 64 + 32 + l31) * 8]); \
    B0 = *(const bf16x8*)(&it[ib + (size_t)(hy_ * 130 + l31 + kx_) * 8]);      \
    B1 = *(const bf16x8*)(&it[ib + (size_t)(hy_ * 130 + 32 + l31 + kx_) * 8]); \
    B2 = *(const bf16x8*)(&it[ib + (size_t)(hy_ * 130 + 64 + l31 + kx_) * 8]); \
    B3 = *(const bf16x8*)(&it[ib + (size_t)(hy_ * 130 + 96 + l31 + kx_) * 8]); \
  }

#define MFMA_TAP(A0, A1, B0, B1, B2, B3)                                       \
  {                                                                            \
    PRIO1;                                                                     \
    acc[0][0] = __builtin_amdgcn_mfma_f32_32x32x16_bf16(A0, B0, acc[0][0], 0, 0, 0); \
    acc[0][1] = __builtin_amdgcn_mfma_f32_32x32x16_bf16(A0, B1, acc[0][1], 0, 0, 0); \
    acc[0][2] = __builtin_amdgcn_mfma_f32_32x32x16_bf16(A0, B2, acc[0][2], 0, 0, 0); \
    acc[0][3] = __builtin_amdgcn_mfma_f32_32x32x16_bf16(A0, B3, acc[0][3], 0, 0, 0); \
    acc[1][0] = __builtin_amdgcn_mfma_f32_32x32x16_bf16(A1, B0, acc[1][0], 0, 0, 0); \
    acc[1][1] = __builtin_amdgcn_mfma_f32_32x32x16_bf16(A1, B1, acc[1][1], 0, 0, 0); \
    acc[1][2] = __builtin_amdgcn_mfma_f32_32x32x16_bf16(A1, B2, acc[1][2], 0, 0, 0); \
    acc[1][3] = __builtin_amdgcn_mfma_f32_32x32x16_bf16(A1, B3, acc[1][3], 0, 0, 0); \
    PRIO0;                                                                     \
  }

    // preload taps 0,1 (buf[cur] is ready: chunk-end VMCNT0+BAR behind us)
    LD_TAP(0, xa0, xa1, xb0, xb1, xb2, xb3);
    LD_TAP(1, ya0, ya1, yb0, yb1, yb2, yb3);
    SCHEDB;

    // ---- PHASE 0: taps 0-2; stage ALL 8 ops for chunk k+1
    if (more) {
#pragma unroll
      for (int i = 0; i < 8; ++i)
        gl_lds16(gb[i] + (size_t)(cic + 1) * gst[i],
                 ld0[i] + (size_t)nbuf * lst[i]);
    }
    SCHEDB;
    BAR;
    MFMA_TAP(xa0, xa1, xb0, xb1, xb2, xb3);   // tap 0
    LD_TAP(2, xa0, xa1, xb0, xb1, xb2, xb3);
    SCHEDB;
    MFMA_TAP(ya0, ya1, yb0, yb1, yb2, yb3);   // tap 1
    LD_TAP(3, ya0, ya1, yb0, yb1, yb2, yb3);
    SCHEDB;
    MFMA_TAP(xa0, xa1, xb0, xb1, xb2, xb3);   // tap 2
    LD_TAP(4, xa0, xa1, xb0, xb1, xb2, xb3);
    SCHEDB;

    // ---- PHASE 1: taps 3-5
    BAR;
    MFMA_TAP(ya0, ya1, yb0, yb1, yb2, yb3);   // tap 3
    LD_TAP(5, ya0, ya1, yb0, yb1, yb2, yb3);
    SCHEDB;
    MFMA_TAP(xa0, xa1, xb0, xb1, xb2, xb3);   // tap 4
    LD_TAP(6, xa0, xa1, xb0, xb1, xb2, xb3);
    SCHEDB;
    MFMA_TAP(ya0, ya1, yb0, yb1, yb2, yb3);   // tap 5
    LD_TAP(7, ya0, ya1, yb0, yb1, yb2, yb3);
    SCHEDB;

    // ---- PHASE 2: taps 6-8
    BAR;
    MFMA_TAP(xa0, xa1, xb0, xb1, xb2, xb3);   // tap 6
    LD_TAP(8, xa0, xa1, xb0, xb1, xb2, xb3);
    SCHEDB;
    MFMA_TAP(ya0, ya1, yb0, yb1, yb2, yb3);   // tap 7
    SCHEDB;
    MFMA_TAP(xa0, xa1, xb0, xb1, xb2, xb3);   // tap 8
#undef LD_TAP
#undef MFMA_TAP

    SCHEDB;
    LGKM0;   // my ds_reads retired
    VMCNT0;  // chunk-(k+1) staging landed (ops issued ~2 phases ago)
    BAR;     // chunk end: buffers safe to swap
    SCHEDB;
  }

  // ---- epilogue. D: col(px)=lane&31, row(co)=(r&3)+8*(r>>2)+4*kh
  const int gyo = y0 + wrow;
  float pd[4][2] = {};  // [fp][cls] (FUSE_DS)
#pragma unroll
  for (int fc = 0; fc < 2; ++fc) {
#pragma unroll
    for (int fp = 0; fp < 4; ++fp) {
      const int px = fp * 32 + l31;
      if constexpr (!FUSE_DS) {
#pragma unroll
        for (int rg = 0; rg < 4; ++rg) {
          const int co0 = wco * 64 + fc * 32 + rg * 8 + kh * 4;
          unsigned short pk[4];
#pragma unroll
          for (int q = 0; q < 4; ++q) {
            float v = acc[fc][fp][rg * 4 + q] + sb[co0 + q];
            v = v > 0.f ? v : 0.01f * v;
            pk[q] = f2bf(v);
          }
          uint2 o;
          o.x = (unsigned)pk[0] | ((unsigned)pk[1] << 16);
          o.y = (unsigned)pk[2] | ((unsigned)pk[3] << 16);
          *(uint2*)(&dst_bf16[(((long)(b * 128 + gyo) * 16 + (co0 >> 3)) * 130 + px + 1) * 8 +
                              kh * 4]) = o;
        }
      } else {
#pragma unroll
        for (int rg = 0; rg < 4; ++rg) {
          const int co0 = wco * 64 + fc * 32 + rg * 8 + kh * 4;
          float4 wv0 = *(const float4*)(&w0s[co0]);
          float4 wv1 = *(const float4*)(&w1s[co0]);
#pragma unroll
          for (int q = 0; q < 4; ++q) {
            float v = acc[fc][fp][rg * 4 + q] + sb[co0 + q];
            v = v > 0.f ? v : 0.01f * v;
            dst_f32[((long)(b * 128 + co0 + q) << 14) + (gyo << 7) + px] = v;
            float wq0 = (q == 0) ? wv0.x : (q == 1) ? wv0.y : (q == 2) ? wv0.z : wv0.w;
            float wq1 = (q == 0) ? wv1.x : (q == 1) ? wv1.y : (q == 2) ? wv1.z : wv1.w;
            pd[fp][0] += wq0 * v;
            pd[fp][1] += wq1 * v;
          }
        }
      }
    }
  }

  if constexpr (!FUSE_DS) {  // zero px 0,129 of this block's 4 rows, all cig
    if (tid < 128) {
      int row = tid >> 5, g = (tid >> 1) & 15;
      long col = (tid & 1) * 129L;
      *(uint4*)(&dst_bf16[(((long)(b * 128 + y0 + row) * 16 + g) * 130 + col) * 8]) =
          make_uint4(0, 0, 0, 0);
    }
  } else {
    // reduce kh (lane^32), then wco pairs via LDS scratch
#pragma unroll
    for (int fp = 0; fp < 4; ++fp)
#pragma unroll
      for (int c = 0; c < 2; ++c)
        pd[fp][c] += __shfl_xor(pd[fp][c], 32, 64);
    if (wco == 1 && kh == 0) {
#pragma unroll
      for (int fp = 0; fp < 4; ++fp)
#pragma unroll
        for (int c = 0; c < 2; ++c)
          sc[((wrow * 4 + fp) * 2 + c) * 32 + l31] = pd[fp][c];
    }
    __syncthreads();
    if (wco == 0 && kh == 0) {
      const int* tb = tar + (long)b * 16384;
#pragma unroll
      for (int fp = 0; fp < 4; ++fp) {
        const int px = fp * 32 + l31;
        float a0 = pd[fp][0] + sc[((wrow * 4 + fp) * 2 + 0) * 32 + l31];
        float a1 = pd[fp][1] + sc[((wrow * 4 + fp) * 2 + 1) * 32 + l31];
        ds[((long)b * 2) * 16384 + (gyo << 7) + px] = a0;
        ds[((long)b * 2 + 1) * 16384 + (gyo << 7) + px] = a1;
        float m = fmaxf(a0, a1);
        float e0 = expf(a0 - m), e1 = expf(a1 - m);
        float s = e0 + e1;
        float p0f = e0 / s, p1f = e1 / s;
        float ent = -(p0f * log2f(p0f + 1e-6f) + p1f * log2f(p1f + 1e-6f));
        float un = ent >= 0.001f ? 1.f : 0.f;
        float pro = 1.f;
        if (gyo > 0 && gyo < 127 && px > 0 && px < 127) {
          int c = tb[(gyo << 7) + px];
          if (c != 0) {
            int nb2 = tb[((gyo - 1) << 7) + px] + tb[((gyo + 1) << 7) + px] +
                      tb[(gyo << 7) + px - 1] + tb[(gyo << 7) + px + 1];
            if (4 * c != nb2) pro = 0.f;
          }
        }
        amap[((long)(b * 128 + gyo) << 7) + px] = un * pro;
      }
    }
  }
}

extern "C" void kernel_launch(void* const* d_in, const int* in_sizes, int n_in,
                              void* d_out, int out_size, void* d_ws, size_t ws_size,
                              hipStream_t stream) {
  const float* x    = (const float*)d_in[0];
  const float* skip = (const float*)d_in[1];
  const int*   tar  = (const int*)d_in[2];
  const float* W1   = (const float*)d_in[3];
  const float* b1   = (const float*)d_in[4];
  const float* W2   = (const float*)d_in[5];
  const float* b2   = (const float*)d_in[6];
  const float* Wds  = (const float*)d_in[7];

  float* out_h  = (float*)d_out;            // 16777216 f32 (h, NCHW)
  float* out_ds = out_h + 16777216;         // 262144 f32
  float* out_am = out_ds + 262144;          // 131072 f32

  // ws: W1b | W2b | zp | (1MB) h1  [8][128][16][130][8] bf16 (34.1MB)
  unsigned short* W1b = (unsigned short*)d_ws;
  unsigned short* W2b = W1b + 294912;
  unsigned short* zp  = W2b + 147456;
  unsigned short* h1  = (unsigned short*)((char*)d_ws + (1u << 20));

  // h0: [8][128][32][130][8] bf16 = 68.2MB, lives in d_out (68.7MB);
  // fully dead before conv2 overwrites d_out (h/ds/amap regions).
  unsigned short* h0 = (unsigned short*)d_out;

  prep<<<3777, 256, 0, stream>>>(x, skip, W1, W2, h0, W1b, W2b, zp);
  conv3x3<256, false><<<256, 512, 0, stream>>>(h0, W1b, b1, zp, h1, nullptr,
                                               nullptr, nullptr, nullptr, nullptr);
  conv3x3<128, true><<<256, 512, 0, stream>>>(h1, W2b, b2, zp, nullptr, out_h,
                                              Wds, tar, out_ds, out_am);
}

// Round 17
// 141.323 us; speedup vs baseline: 1.2615x; 1.0105x over previous
//
#include <hip/hip_runtime.h>

typedef float f32x16 __attribute__((ext_vector_type(16)));
typedef short bf16x8 __attribute__((ext_vector_type(8)));
typedef unsigned int u32;

static __device__ __forceinline__ unsigned short f2bf(float f) {
  union { float f; unsigned int u; } v;
  v.f = f;
  return (unsigned short)((v.u + 0x7FFFu + ((v.u >> 16) & 1u)) >> 16);
}

// async 16B global->LDS (DMA). LDS dest = wave-uniform base + lane*16.
static __device__ __forceinline__ void gl_lds16(const unsigned short* g,
                                                unsigned short* l) {
  __builtin_amdgcn_global_load_lds(
      (const __attribute__((address_space(1))) u32*)g,
      (__attribute__((address_space(3))) u32*)l, 16, 0, 0);
}

#define VMCNT0 asm volatile("s_waitcnt vmcnt(0)" ::: "memory")
#define LGKM0 asm volatile("s_waitcnt lgkmcnt(0)" ::: "memory")
#define BAR __builtin_amdgcn_s_barrier()
#define SCHEDB __builtin_amdgcn_sched_barrier(0)
#define PRIO1 __builtin_amdgcn_s_setprio(1)
#define PRIO0 __builtin_amdgcn_s_setprio(0)

// ---- prep: merged transpose (blocks 0..2047) + weight convert (2048..3776)
// transpose: NCHW fp32 -> padded plane-major bf16, via float4 coalesced
// reads + padded-LDS channel-gather (G13: no scalar 4B global loads).
// weights: OIHW fp32 -> [cic][p][tap][co][8ci] bf16 slabs; + zero page.
__global__ __launch_bounds__(256) void prep(
    const float* __restrict__ x, const float* __restrict__ skip,
    const float* __restrict__ W1, const float* __restrict__ W2,
    unsigned short* __restrict__ dst, unsigned short* __restrict__ W1b,
    unsigned short* __restrict__ W2b, unsigned short* __restrict__ zp) {
  const int bid = blockIdx.x;
  if (bid >= 2048) {
    const int cb = bid - 2048;
    if (cb == 1728) {  // zero the 8KB zero page
      uint4* z = (uint4*)zp;
      z[threadIdx.x] = make_uint4(0, 0, 0, 0);
      z[256 + threadIdx.x] = make_uint4(0, 0, 0, 0);
      return;
    }
    int i = cb * 256 + (int)threadIdx.x;
    if (i < 294912) {
      int e = i & 7, co = (i >> 3) & 127, r = i >> 10;  // r=(cic*2+p)*9+tap
      int tap = r % 9, pc = r / 9;
      int ci = (pc >> 1) * 16 + (pc & 1) * 8 + e;
      W1b[i] = f2bf(W1[(co * 256 + ci) * 9 + tap]);
    } else {
      int j = i - 294912;
      if (j < 147456) {
        int e = j & 7, co = (j >> 3) & 127, r = j >> 10;
        int tap = r % 9, pc = r / 9;
        int ci = (pc >> 1) * 16 + (pc & 1) * 8 + e;
        W2b[j] = f2bf(W2[(co * 128 + ci) * 9 + tap]);
      }
    }
    return;
  }
  // ---- transpose one (source,row): two 64-channel halves through LDS
  __shared__ float4 lsf[64][33];  // [ch][px-quad], pad 1 quad -> conflict-free
  const float* src = (bid < 1024) ? x : skip;
  const int cigb = (bid < 1024) ? 0 : 16;
  const int row = bid & 1023;  // b*128+y
  const int b = row >> 7, y = row & 127;
  const float* s = src + (long)b * 128 * 16384 + (long)y * 128;
  unsigned short* drow = dst + ((long)row * 32 + cigb) * 130 * 8;
#pragma unroll
  for (int half = 0; half < 2; ++half) {
    const float* sh = s + (long)half * 64 * 16384;
    // stage 64ch x 128px as float4 (16B/lane coalesced)
#pragma unroll
    for (int i = 0; i < 8; ++i) {
      int idx = i * 256 + (int)threadIdx.x;  // 2048 quads
      int c = idx >> 5, q = idx & 31;
      lsf[c][q] = *(const float4*)(sh + (long)c * 16384 + q * 4);
    }
    __syncthreads();
    // emit 8 cig x 128 px (LDS gather: banks (4e+px)%32 -> 2 lanes/bank)
    const float* col = (const float*)&lsf[0][0];
#pragma unroll
    for (int j = 0; j < 4; ++j) {
      int o = j * 256 + (int)threadIdx.x;  // 1024 outputs
      int cig = o >> 7, px = o & 127;
      unsigned short pk[8];
#pragma unroll
      for (int e = 0; e < 8; ++e)
        pk[e] = f2bf(col[(cig * 8 + e) * 132 + px]);
      uint4 vv;
      vv.x = (unsigned)pk[0] | ((unsigned)pk[1] << 16);
      vv.y = (unsigned)pk[2] | ((unsigned)pk[3] << 16);
      vv.z = (unsigned)pk[4] | ((unsigned)pk[5] << 16);
      vv.w = (unsigned)pk[6] | ((unsigned)pk[7] << 16);
      *(uint4*)(&drow[((long)(half * 8 + cig) * 130 + px + 1) * 8]) = vv;
    }
    __syncthreads();
  }
  if (cigb == 0 && threadIdx.x < 64) {  // zero px 0,129 for all 32 cig
    int g = threadIdx.x >> 1;
    long col2 = (threadIdx.x & 1) * 129L;
    *(uint4*)(&dst[(((long)row * 32 + g) * 130 + col2) * 8]) = make_uint4(0, 0, 0, 0);
  }
}

// ---------------- 3x3 SAME conv, implicit GEMM, bf16 MFMA -----------------
// block = 4 rows x 128 co x 128 px, 8 waves (wco 2 x wrow 4), 512 thr.
// R15 schedule (best measured): fully double-buffered staging, chunk = 3
// phases (3 taps each) with a barrier per phase, staging spread 4/4/0 across
// phases (loads in flight across barriers, T4), setprio(1) wrapping each
// phase's MFMA+LD region (T5), 2-deep tap register pipeline.
template <int CIN, bool FUSE_DS>
__global__ __launch_bounds__(512, 2) void conv3x3(
    const unsigned short* __restrict__ src,  // [8][128][CIN/8][130][8]
    const unsigned short* __restrict__ wt,   // [cic][p][tap][co][8]
    const float* __restrict__ bias,          // [128]
    const unsigned short* __restrict__ zp,   // zeroed 8KB
    unsigned short* __restrict__ dst_bf16,   // [8][128][16][130][8]
    float* __restrict__ dst_f32,             // NCHW fp32 [8,128,128,128]
    const float* __restrict__ wds,           // [2,128] (FUSE_DS)
    const int* __restrict__ tar,             // [8,128,128] (FUSE_DS)
    float* __restrict__ ds,                  // [8,2,128,128] (FUSE_DS)
    float* __restrict__ amap) {              // [8,128,128] (FUSE_DS)
  constexpr int CPG = CIN / 8;
  constexpr int NC = CIN / 16;
  __shared__ unsigned short in_tile[2][1664 * 8];  // 2 x 26 KB
  __shared__ unsigned short wt_tile[2][2304 * 8];  // 2 x 36.9 KB
  __shared__ unsigned short scr[64 * 8];           // dummy-op sink, 1 KB
  __shared__ float sb[128];
  __shared__ float w0s[128], w1s[128];
  __shared__ float sc[4 * 4 * 2 * 32];

  const int tid = threadIdx.x;
  // XCD-aware bijective swizzle: 256 blocks = 8 XCDs x 32 contiguous
  const int wg = (blockIdx.x & 7) * 32 + (blockIdx.x >> 3);
  const int b = wg >> 5;
  const int y0 = (wg & 31) * 4;
  const int lane = tid & 63, wave = tid >> 6;
  const int wco = wave & 1, wrow = wave >> 1;
  const int l31 = lane & 31, kh = lane >> 5;

  if (tid < 128) {
    sb[tid] = bias[tid];
    if constexpr (FUSE_DS) {
      w0s[tid] = wds[tid];
      w1s[tid] = wds[128 + tid];
    }
  }

  // ---- flat op table: ops 0..35 = wt slab, 36..61 = input, 62..63 dummy
  const unsigned short* gb[8];
  unsigned short* ld0[8];
  int gst[8];
  int lst[8];
#pragma unroll
  for (int i = 0; i < 8; ++i) {
    const int o = wave * 8 + i;
    if (o < 36) {
      gb[i] = wt + o * 512 + lane * 8;
      gst[i] = 18432;
      ld0[i] = &wt_tile[0][(size_t)o * 512];
      lst[i] = 18432;
    } else if (o < 62) {
      const int q = o - 36;
      const int p = q / 13, j = q - p * 13;
      const int s = j * 64 + lane;
      const int hy = s / 130, hx = s - hy * 130;
      const int gy = y0 - 1 + hy;
      const bool ok = (s < 780) && (gy >= 0) && (gy < 128);
      gb[i] = ok ? src + ((size_t)((b * 128 + gy) * CPG) + p) * 1040 + hx * 8
                 : zp + lane * 8;
      gst[i] = ok ? 2080 : 0;
      ld0[i] = &in_tile[0][(size_t)(p * 832 + j * 64) * 8];
      lst[i] = 1664 * 8;
    } else {
      gb[i] = zp + lane * 8;
      gst[i] = 0;
      ld0[i] = &scr[0];
      lst[i] = 0;
    }
  }

  f32x16 acc[2][4] = {};

  // prologue: stage chunk 0 into buf 0
#pragma unroll
  for (int i = 0; i < 8; ++i) gl_lds16(gb[i], ld0[i]);
  VMCNT0;
  LGKM0;
  BAR;
  SCHEDB;

  for (int cic = 0; cic < NC; ++cic) {
    const int cur = cic & 1;
    const int nbuf = cur ^ 1;
    const bool more = (cic + 1 < NC);

    const unsigned short* it = &in_tile[cur][0];
    const unsigned short* wl = &wt_tile[cur][0];
    const size_t ib = (size_t)kh * (832 * 8);
    const size_t wb = (size_t)kh * 9216;

    bf16x8 xa0, xa1, xb0, xb1, xb2, xb3;  // even-tap set
    bf16x8 ya0, ya1, yb0, yb1, yb2, yb3;  // odd-tap set

#define LD_TAP(T, A0, A1, B0, B1, B2, B3)                                      \
  {                                                                            \
    constexpr int ky_ = (T) / 3, kx_ = (T) % 3;                                \
    const int hy_ = ky_ + wrow;                                                \
    A0 = *(const bf16x8*)(&wl[wb + (size_t)((T)*128 + wco * 64 + l31) * 8]);   \
    A1 = *(const bf16x8*)(&wl[wb + (size_t)((T)*128 + wco * 64 + 32 + l31) * 8]); \
    B0 = *(const bf16x8*)(&it[ib + (size_t)(hy_ * 130 + l31 + kx_) * 8]);      \
    B1 = *(const bf16x8*)(&it[ib + (size_t)(hy_ * 130 + 32 + l31 + kx_) * 8]); \
    B2 = *(const bf16x8*)(&it[ib + (size_t)(hy_ * 130 + 64 + l31 + kx_) * 8]); \
    B3 = *(const bf16x8*)(&it[ib + (size_t)(hy_ * 130 + 96 + l31 + kx_) * 8]); \
  }

#define MFMA_TAP(A0, A1, B0, B1, B2, B3)                                       \
  {                                                                            \
    acc[0][0] = __builtin_amdgcn_mfma_f32_32x32x16_bf16(A0, B0, acc[0][0], 0, 0, 0); \
    acc[0][1] = __builtin_amdgcn_mfma_f32_32x32x16_bf16(A0, B1, acc[0][1], 0, 0, 0); \
    acc[0][2] = __builtin_amdgcn_mfma_f32_32x32x16_bf16(A0, B2, acc[0][2], 0, 0, 0); \
    acc[0][3] = __builtin_amdgcn_mfma_f32_32x32x16_bf16(A0, B3, acc[0][3], 0, 0, 0); \
    acc[1][0] = __builtin_amdgcn_mfma_f32_32x32x16_bf16(A1, B0, acc[1][0], 0, 0, 0); \
    acc[1][1] = __builtin_amdgcn_mfma_f32_32x32x16_bf16(A1, B1, acc[1][1], 0, 0, 0); \
    acc[1][2] = __builtin_amdgcn_mfma_f32_32x32x16_bf16(A1, B2, acc[1][2], 0, 0, 0); \
    acc[1][3] = __builtin_amdgcn_mfma_f32_32x32x16_bf16(A1, B3, acc[1][3], 0, 0, 0); \
  }

    // preload taps 0,1 (buf[cur] is ready: chunk-end VMCNT0+BAR behind us)
    LD_TAP(0, xa0, xa1, xb0, xb1, xb2, xb3);
    LD_TAP(1, ya0, ya1, yb0, yb1, yb2, yb3);
    SCHEDB;

    // ---- PHASE 0: taps 0-2; stage ops 0-3 for chunk k+1
    if (more) {
#pragma unroll
      for (int i = 0; i < 4; ++i)
        gl_lds16(gb[i] + (size_t)(cic + 1) * gst[i],
                 ld0[i] + (size_t)nbuf * lst[i]);
    }
    SCHEDB;
    BAR;
    PRIO1;
    MFMA_TAP(xa0, xa1, xb0, xb1, xb2, xb3);   // tap 0
    LD_TAP(2, xa0, xa1, xb0, xb1, xb2, xb3);
    SCHEDB;
    MFMA_TAP(ya0, ya1, yb0, yb1, yb2, yb3);   // tap 1
    LD_TAP(3, ya0, ya1, yb0, yb1, yb2, yb3);
    SCHEDB;
    MFMA_TAP(xa0, xa1, xb0, xb1, xb2, xb3);   // tap 2
    LD_TAP(4, xa0, xa1, xb0, xb1, xb2, xb3);
    SCHEDB;
    PRIO0;

    // ---- PHASE 1: taps 3-5; stage ops 4-7 for chunk k+1
    if (more) {
#pragma unroll
      for (int i = 4; i < 8; ++i)
        gl_lds16(gb[i] + (size_t)(cic + 1) * gst[i],
                 ld0[i] + (size_t)nbuf * lst[i]);
    }
    SCHEDB;
    BAR;
    PRIO1;
    MFMA_TAP(ya0, ya1, yb0, yb1, yb2, yb3);   // tap 3
    LD_TAP(5, ya0, ya1, yb0, yb1, yb2, yb3);
    SCHEDB;
    MFMA_TAP(xa0, xa1, xb0, xb1, xb2, xb3);   // tap 4
    LD_TAP(6, xa0, xa1, xb0, xb1, xb2, xb3);
    SCHEDB;
    MFMA_TAP(ya0, ya1, yb0, yb1, yb2, yb3);   // tap 5
    LD_TAP(7, ya0, ya1, yb0, yb1, yb2, yb3);
    SCHEDB;
    PRIO0;

    // ---- PHASE 2: taps 6-8; no staging
    BAR;
    PRIO1;
    MFMA_TAP(xa0, xa1, xb0, xb1, xb2, xb3);   // tap 6
    LD_TAP(8, xa0, xa1, xb0, xb1, xb2, xb3);
    SCHEDB;
    MFMA_TAP(ya0, ya1, yb0, yb1, yb2, yb3);   // tap 7
    SCHEDB;
    MFMA_TAP(xa0, xa1, xb0, xb1, xb2, xb3);   // tap 8
    PRIO0;
#undef LD_TAP
#undef MFMA_TAP

    SCHEDB;
    LGKM0;   // my ds_reads retired
    VMCNT0;  // chunk-(k+1) staging landed (newest op issued 1+ phase ago)
    BAR;     // chunk end: buffers safe to swap
    SCHEDB;
  }

  // ---- epilogue. D: col(px)=lane&31, row(co)=(r&3)+8*(r>>2)+4*kh
  const int gyo = y0 + wrow;
  float pd[4][2] = {};  // [fp][cls] (FUSE_DS)
#pragma unroll
  for (int fc = 0; fc < 2; ++fc) {
#pragma unroll
    for (int fp = 0; fp < 4; ++fp) {
      const int px = fp * 32 + l31;
      if constexpr (!FUSE_DS) {
#pragma unroll
        for (int rg = 0; rg < 4; ++rg) {
          const int co0 = wco * 64 + fc * 32 + rg * 8 + kh * 4;
          unsigned short pk[4];
#pragma unroll
          for (int q = 0; q < 4; ++q) {
            float v = acc[fc][fp][rg * 4 + q] + sb[co0 + q];
            v = v > 0.f ? v : 0.01f * v;
            pk[q] = f2bf(v);
          }
          uint2 o;
          o.x = (unsigned)pk[0] | ((unsigned)pk[1] << 16);
          o.y = (unsigned)pk[2] | ((unsigned)pk[3] << 16);
          *(uint2*)(&dst_bf16[(((long)(b * 128 + gyo) * 16 + (co0 >> 3)) * 130 + px + 1) * 8 +
                              kh * 4]) = o;
        }
      } else {
#pragma unroll
        for (int rg = 0; rg < 4; ++rg) {
          const int co0 = wco * 64 + fc * 32 + rg * 8 + kh * 4;
          float4 wv0 = *(const float4*)(&w0s[co0]);
          float4 wv1 = *(const float4*)(&w1s[co0]);
#pragma unroll
          for (int q = 0; q < 4; ++q) {
            float v = acc[fc][fp][rg * 4 + q] + sb[co0 + q];
            v = v > 0.f ? v : 0.01f * v;
            dst_f32[((long)(b * 128 + co0 + q) << 14) + (gyo << 7) + px] = v;
            float wq0 = (q == 0) ? wv0.x : (q == 1) ? wv0.y : (q == 2) ? wv0.z : wv0.w;
            float wq1 = (q == 0) ? wv1.x : (q == 1) ? wv1.y : (q == 2) ? wv1.z : wv1.w;
            pd[fp][0] += wq0 * v;
            pd[fp][1] += wq1 * v;
          }
        }
      }
    }
  }

  if constexpr (!FUSE_DS) {  // zero px 0,129 of this block's 4 rows, all cig
    if (tid < 128) {
      int row = tid >> 5, g = (tid >> 1) & 15;
      long col = (tid & 1) * 129L;
      *(uint4*)(&dst_bf16[(((long)(b * 128 + y0 + row) * 16 + g) * 130 + col) * 8]) =
          make_uint4(0, 0, 0, 0);
    }
  } else {
    // reduce kh (lane^32), then wco pairs via LDS scratch
#pragma unroll
    for (int fp = 0; fp < 4; ++fp)
#pragma unroll
      for (int c = 0; c < 2; ++c)
        pd[fp][c] += __shfl_xor(pd[fp][c], 32, 64);
    if (wco == 1 && kh == 0) {
#pragma unroll
      for (int fp = 0; fp < 4; ++fp)
#pragma unroll
        for (int c = 0; c < 2; ++c)
          sc[((wrow * 4 + fp) * 2 + c) * 32 + l31] = pd[fp][c];
    }
    __syncthreads();
    if (wco == 0 && kh == 0) {
      const int* tb = tar + (long)b * 16384;
#pragma unroll
      for (int fp = 0; fp < 4; ++fp) {
        const int px = fp * 32 + l31;
        float a0 = pd[fp][0] + sc[((wrow * 4 + fp) * 2 + 0) * 32 + l31];
        float a1 = pd[fp][1] + sc[((wrow * 4 + fp) * 2 + 1) * 32 + l31];
        ds[((long)b * 2) * 16384 + (gyo << 7) + px] = a0;
        ds[((long)b * 2 + 1) * 16384 + (gyo << 7) + px] = a1;
        float m = fmaxf(a0, a1);
        float e0 = expf(a0 - m), e1 = expf(a1 - m);
        float s = e0 + e1;
        float p0f = e0 / s, p1f = e1 / s;
        float ent = -(p0f * log2f(p0f + 1e-6f) + p1f * log2f(p1f + 1e-6f));
        float un = ent >= 0.001f ? 1.f : 0.f;
        float pro = 1.f;
        if (gyo > 0 && gyo < 127 && px > 0 && px < 127) {
          int c = tb[(gyo << 7) + px];
          if (c != 0) {
            int nb2 = tb[((gyo - 1) << 7) + px] + tb[((gyo + 1) << 7) + px] +
                      tb[(gyo << 7) + px - 1] + tb[(gyo << 7) + px + 1];
            if (4 * c != nb2) pro = 0.f;
          }
        }
        amap[((long)(b * 128 + gyo) << 7) + px] = un * pro;
      }
    }
  }
}

extern "C" void kernel_launch(void* const* d_in, const int* in_sizes, int n_in,
                              void* d_out, int out_size, void* d_ws, size_t ws_size,
                              hipStream_t stream) {
  const float* x    = (const float*)d_in[0];
  const float* skip = (const float*)d_in[1];
  const int*   tar  = (const int*)d_in[2];
  const float* W1   = (const float*)d_in[3];
  const float* b1   = (const float*)d_in[4];
  const float* W2   = (const float*)d_in[5];
  const float* b2   = (const float*)d_in[6];
  const float* Wds  = (const float*)d_in[7];

  float* out_h  = (float*)d_out;            // 16777216 f32 (h, NCHW)
  float* out_ds = out_h + 16777216;         // 262144 f32
  float* out_am = out_ds + 262144;          // 131072 f32

  // ws: W1b | W2b | zp | (1MB) h1  [8][128][16][130][8] bf16 (34.1MB)
  unsigned short* W1b = (unsigned short*)d_ws;
  unsigned short* W2b = W1b + 294912;
  unsigned short* zp  = W2b + 147456;
  unsigned short* h1  = (unsigned short*)((char*)d_ws + (1u << 20));

  // h0: [8][128][32][130][8] bf16 = 68.2MB, lives in d_out (68.7MB);
  // fully dead before conv2 overwrites d_out (h/ds/amap regions).
  unsigned short* h0 = (unsigned short*)d_out;

  prep<<<3777, 256, 0, stream>>>(x, skip, W1, W2, h0, W1b, W2b, zp);
  conv3x3<256, false><<<256, 512, 0, stream>>>(h0, W1b, b1, zp, h1, nullptr,
                                               nullptr, nullptr, nullptr, nullptr);
  conv3x3<128, true><<<256, 512, 0, stream>>>(h1, W2b, b2, zp, nullptr, out_h,
                                              Wds, tar, out_ds, out_am);
}